// Round 1
// baseline (298.850 us; speedup 1.0000x reference)
//
#include <hip/hip_runtime.h>
#include <stdint.h>

typedef unsigned int u32;
typedef unsigned long long u64;

#define OCC_THR   0.5f
#define RADIUS_F  1.0f
#define MAXT      4096
#define MAXP      8192
#define LDS_CAND  6144
#define K1_TT     128
#define K2_THREADS 512
#define PER       8   // MAXT / K2_THREADS

// ---------------- Kernel 1: build candidate lists ----------------
// For every (true i, pred j) with pred_p[j] >= 0.5 and sqrt(d2) <= 1.0,
// append key = (dist_bits << 32) | j to cands[i*cap ...] via atomic slot.
__global__ void __launch_bounds__(256) k_build(
    const float4* __restrict__ pred, const float4* __restrict__ tru,
    int n_pred, int n_true, int cap,
    u32* __restrict__ counts, u64* __restrict__ cands)
{
    __shared__ float4 st[K1_TT];
    const int tid = threadIdx.x;
    const int j   = blockIdx.x * 256 + tid;
    const int ti0 = blockIdx.y * K1_TT;

    for (int t = tid; t < K1_TT; t += 256) {
        int i = ti0 + t;
        st[t] = (i < n_true) ? tru[i] : make_float4(1e30f, 1e30f, 1e30f, 0.0f);
    }
    __syncthreads();

    if (j >= n_pred) return;
    const float4 p = pred[j];
    if (!(p.w >= OCC_THR)) return;

    const int tmax = min(K1_TT, n_true - ti0);
    for (int t = 0; t < tmax; ++t) {
        float4 q = st[t];
        float dx = q.x - p.x, dy = q.y - p.y, dz = q.z - p.z;
        float d2 = dx*dx + dy*dy + dz*dz;
        float d  = sqrtf(d2);
        if (d <= RADIUS_F) {
            int i = ti0 + t;
            u32 slot = atomicAdd(&counts[i], 1u);
            if ((int)slot < cap) {
                u64 key = ((u64)__float_as_uint(d) << 32) | (u32)j;
                cands[(size_t)i * (size_t)cap + slot] = key;
            }
        }
    }
}

// ---------------- Kernel 2: exact serial greedy matching ----------------
__global__ void __launch_bounds__(K2_THREADS) k_match(
    const float4* __restrict__ pred, const float4* __restrict__ tru,
    int n_pred, int n_true, int cap,
    const u32* __restrict__ counts,
    const u64* __restrict__ cands,
    float* __restrict__ out)
{
    __shared__ float s_pp[MAXP];          // 32 KB  pred probabilities
    __shared__ u64   s_cand[LDS_CAND];    // 48 KB  compacted candidate keys
    __shared__ u64   s_meta[MAXT];        // 32 KB  per-active-true metadata
    __shared__ unsigned char s_sup[MAXP]; //  8 KB  suppression map
    __shared__ u32   s_scan[K2_THREADS];  //  2 KB  block scan
    __shared__ int   s_numtrue;

    const int tid = threadIdx.x;
    if (tid == 0) s_numtrue = 0;

    for (int j = tid; j < n_pred; j += K2_THREADS) {
        s_pp[j]  = pred[j].w;
        s_sup[j] = 0;
    }
    __syncthreads();

    // Per-thread segment of true points: flags, counts, probs
    u32 effs[PER], acts[PER];
    float tps[PER];
    u32 vals[PER];
    int myvalid = 0;
#pragma unroll
    for (int k = 0; k < PER; ++k) {
        int i = tid * PER + k;
        u32 eff = 0, act = 0; float tp = 0.0f;
        if (i < n_true) {
            float4 q = tru[i];
            tp = q.w;
            bool valid = (q.w >= OCC_THR);
            myvalid += valid ? 1 : 0;
            u32 c = counts[i];
            if (c > (u32)cap) c = (u32)cap;
            if (valid && c > 0u) { act = 1u; eff = c; }
        }
        effs[k] = eff; acts[k] = act; tps[k] = tp;
        vals[k] = eff | (act << 19);   // low19: cand count, high13: active flag
    }
    // local exclusive scan
    u32 run = 0, excl[PER];
#pragma unroll
    for (int k = 0; k < PER; ++k) { excl[k] = run; run += vals[k]; }
    const u32 ttotal = run;
    if (myvalid) atomicAdd(&s_numtrue, myvalid);

    s_scan[tid] = ttotal;
    __syncthreads();
    for (int off = 1; off < K2_THREADS; off <<= 1) {
        u32 v   = s_scan[tid];
        u32 add = (tid >= off) ? s_scan[tid - off] : 0u;
        __syncthreads();
        s_scan[tid] = v + add;
        __syncthreads();
    }
    const u32 base  = s_scan[tid] - ttotal;
    const u32 grand = s_scan[K2_THREADS - 1];

    // compact metadata + candidates into LDS
#pragma unroll
    for (int k = 0; k < PER; ++k) {
        if (!acts[k]) continue;
        int i = tid * PER + k;
        u32 pref = base + excl[k];
        u32 coff = pref & 0x7FFFFu;
        u32 pos  = pref >> 19;
        u32 eff  = effs[k];
        u32 cf   = (coff + eff <= (u32)LDS_CAND) ? coff : 0x1FFFu; // sentinel -> global path
        u64 meta = ((u64)__float_as_uint(tps[k]) << 32)
                 | ((u64)(u32)i << 20) | ((u64)cf << 7) | (u64)eff;
        s_meta[pos] = meta;
        if (cf != 0x1FFFu) {
            for (u32 kk = 0; kk < eff; ++kk)
                s_cand[coff + kk] = cands[(size_t)i * (size_t)cap + kk];
        }
    }
    __syncthreads();

    if (tid != 0) return;

    // serial greedy over active true points only (index order preserved)
    float sum_dist = 0.0f, sum_sq = 0.0f;
    int   cnt = 0;
    const u32 nact = grand >> 19;
    for (u32 e = 0; e < nact; ++e) {
        u64 m    = s_meta[e];
        u32 eff  = (u32)(m & 0x7Fu);
        u32 coff = (u32)((m >> 7) & 0x1FFFu);
        u32 i    = (u32)((m >> 20) & 0xFFFu);
        float tp = __uint_as_float((u32)(m >> 32));
        u64 best = ~0ull;
        if (coff != 0x1FFFu) {
            for (u32 kk = 0; kk < eff; ++kk) {
                u64 c = s_cand[coff + kk];
                if (!s_sup[(u32)c] && c < best) best = c;
            }
        } else {
            for (u32 kk = 0; kk < eff; ++kk) {
                u64 c = cands[(size_t)i * (size_t)cap + kk];
                if (!s_sup[(u32)c] && c < best) best = c;
            }
        }
        if (best != ~0ull) {
            u32 j  = (u32)best;
            float d = __uint_as_float((u32)(best >> 32));
            s_sup[j] = 1;
            sum_dist += d;
            float diff = tp - s_pp[j];
            sum_sq += diff * diff;
            cnt++;
        }
    }

    float num_true  = (float)s_numtrue;
    float cnt_f     = (float)cnt;
    float unmatched = num_true - cnt_f;
    float denom     = fmaxf(cnt_f, 1.0f);
    bool  has       = cnt > 0;
    float spatial   = RADIUS_F * 10.0f * unmatched + (has ? sum_dist / denom : 0.0f);
    float prob      = unmatched + (has ? sum_sq / denom : 0.0f);
    out[0] = spatial + prob;
}

// ---------------- launch ----------------
extern "C" void kernel_launch(void* const* d_in, const int* in_sizes, int n_in,
                              void* d_out, int out_size, void* d_ws, size_t ws_size,
                              hipStream_t stream) {
    const float4* pred = (const float4*)d_in[0];
    const float4* tru  = (const float4*)d_in[1];
    const int n_pred = in_sizes[0] / 4;
    const int n_true = in_sizes[1] / 4;

    u32* counts = (u32*)d_ws;
    size_t counts_bytes = (size_t)n_true * sizeof(u32);
    size_t cand_off = (counts_bytes + 255) & ~(size_t)255;
    u64* cands = (u64*)((char*)d_ws + cand_off);

    int cap = 64;
    size_t need = cand_off + (size_t)n_true * (size_t)cap * 8;
    if (need > ws_size) {
        size_t avail = (ws_size > cand_off) ? (ws_size - cand_off) : 0;
        long c = (long)(avail / ((size_t)n_true * 8));
        cap = (int)(c < 1 ? 1 : (c > 64 ? 64 : c));
    }

    hipMemsetAsync(d_ws, 0, counts_bytes, stream);

    dim3 g1((n_pred + 255) / 256, (n_true + K1_TT - 1) / K1_TT);
    k_build<<<g1, 256, 0, stream>>>(pred, tru, n_pred, n_true, cap, counts, cands);
    k_match<<<1, K2_THREADS, 0, stream>>>(pred, tru, n_pred, n_true, cap, counts, cands,
                                          (float*)d_out);
}

// Round 2
// 151.443 us; speedup vs baseline: 1.9733x; 1.9733x over previous
//
#include <hip/hip_runtime.h>
#include <stdint.h>

typedef unsigned int u32;
typedef unsigned long long u64;

#define OCC_THR   0.5f
#define RADIUS_F  1.0f
#define MAXT      4096
#define MAXP      8192
#define LDS_CAND  6144
#define K1_TT     128
#define K2_THREADS 512
#define PER       8   // MAXT / K2_THREADS

// ---------------- Kernel 1: build candidate lists ----------------
__global__ void __launch_bounds__(256) k_build(
    const float4* __restrict__ pred, const float4* __restrict__ tru,
    int n_pred, int n_true, int cap,
    u32* __restrict__ counts, u64* __restrict__ cands)
{
    __shared__ float4 st[K1_TT];
    const int tid = threadIdx.x;
    const int j   = blockIdx.x * 256 + tid;
    const int ti0 = blockIdx.y * K1_TT;

    for (int t = tid; t < K1_TT; t += 256) {
        int i = ti0 + t;
        st[t] = (i < n_true) ? tru[i] : make_float4(1e30f, 1e30f, 1e30f, 0.0f);
    }
    __syncthreads();

    if (j >= n_pred) return;
    const float4 p = pred[j];
    if (!(p.w >= OCC_THR)) return;

    const int tmax = min(K1_TT, n_true - ti0);
    for (int t = 0; t < tmax; ++t) {
        float4 q = st[t];
        float dx = q.x - p.x, dy = q.y - p.y, dz = q.z - p.z;
        float d2 = dx*dx + dy*dy + dz*dz;
        float d  = sqrtf(d2);
        if (d <= RADIUS_F) {
            int i = ti0 + t;
            u32 slot = atomicAdd(&counts[i], 1u);
            if ((int)slot < cap) {
                u64 key = ((u64)__float_as_uint(d) << 32) | (u32)j;
                cands[(size_t)i * (size_t)cap + slot] = key;
            }
        }
    }
}

// ---------------- Kernel 2: wave-parallel exact greedy matching ----------------
__global__ void __launch_bounds__(K2_THREADS) k_match(
    const float4* __restrict__ pred, const float4* __restrict__ tru,
    int n_pred, int n_true, int cap,
    const u32* __restrict__ counts,
    const u64* __restrict__ cands,
    float* __restrict__ out)
{
    __shared__ float s_pp[MAXP];          // 32 KB
    __shared__ u64   s_cand[LDS_CAND];    // 48 KB
    __shared__ u64   s_meta[MAXT];        // 32 KB
    __shared__ unsigned char s_sup[MAXP]; //  8 KB
    __shared__ u32   s_scan[K2_THREADS];  //  2 KB
    __shared__ int   s_numtrue;

    const int tid = threadIdx.x;
    if (tid == 0) s_numtrue = 0;

    for (int j = tid; j < n_pred; j += K2_THREADS) {
        s_pp[j]  = pred[j].w;
        s_sup[j] = 0;
    }
    __syncthreads();

    // ---- prologue: per-thread segment of true points ----
    u32 effs[PER], acts[PER];
    float tps[PER];
    u32 vals[PER];
    int myvalid = 0;
#pragma unroll
    for (int k = 0; k < PER; ++k) {
        int i = tid * PER + k;
        u32 eff = 0, act = 0; float tp = 0.0f;
        if (i < n_true) {
            float4 q = tru[i];
            tp = q.w;
            bool valid = (q.w >= OCC_THR);
            myvalid += valid ? 1 : 0;
            u32 c = counts[i];
            if (c > (u32)cap) c = (u32)cap;
            if (valid && c > 0u) { act = 1u; eff = c; }
        }
        effs[k] = eff; acts[k] = act; tps[k] = tp;
        vals[k] = eff | (act << 19);
    }
    u32 run = 0, excl[PER];
#pragma unroll
    for (int k = 0; k < PER; ++k) { excl[k] = run; run += vals[k]; }
    const u32 ttotal = run;
    if (myvalid) atomicAdd(&s_numtrue, myvalid);

    s_scan[tid] = ttotal;
    __syncthreads();
    for (int off = 1; off < K2_THREADS; off <<= 1) {
        u32 v   = s_scan[tid];
        u32 add = (tid >= off) ? s_scan[tid - off] : 0u;
        __syncthreads();
        s_scan[tid] = v + add;
        __syncthreads();
    }
    const u32 base  = s_scan[tid] - ttotal;
    const u32 grand = s_scan[K2_THREADS - 1];

    // ---- compact metadata + candidates into LDS ----
#pragma unroll
    for (int k = 0; k < PER; ++k) {
        if (!acts[k]) continue;
        int i = tid * PER + k;
        u32 pref = base + excl[k];
        u32 coff = pref & 0x7FFFFu;
        u32 pos  = pref >> 19;
        u32 eff  = effs[k];
        u32 cf   = (coff + eff <= (u32)LDS_CAND) ? coff : 0x1FFFu;
        u64 meta = ((u64)__float_as_uint(tps[k]) << 32)
                 | ((u64)(u32)i << 20) | ((u64)cf << 7) | (u64)eff;
        s_meta[pos] = meta;
        if (cf != 0x1FFFu) {
            for (u32 kk = 0; kk < eff; ++kk)
                s_cand[coff + kk] = cands[(size_t)i * (size_t)cap + kk];
        }
    }
    __syncthreads();

    if (tid >= 64) return;   // wave 0 only from here (no further barriers)
    const u32 lane = (u32)tid;
    const int num_true_i = s_numtrue;

    float my_sum_dist = 0.0f, my_sum_sq = 0.0f;
    int   my_cnt = 0;
    const u32 nact = grand >> 19;

    for (u32 ebase = 0; ebase < nact; ebase += 64) {
        const u32 e = ebase + lane;
        u64 best = ~0ull;
        u32 eff = 0, coff = 0x1FFFu, gi = 0;
        float tp = 0.0f;
        if (e < nact) {
            u64 m = s_meta[e];
            eff  = (u32)(m & 0x7Fu);
            coff = (u32)((m >> 7) & 0x1FFFu);
            gi   = (u32)((m >> 20) & 0xFFFu);
            tp   = __uint_as_float((u32)(m >> 32));
            if (coff != 0x1FFFu) {
                for (u32 kk = 0; kk < eff; ++kk) {
                    u64 c = s_cand[coff + kk];
                    if (!s_sup[(u32)c] && c < best) best = c;
                }
            } else {
                for (u32 kk = 0; kk < eff; ++kk) {
                    u64 c = cands[(size_t)gi * (size_t)cap + kk];
                    if (!s_sup[(u32)c] && c < best) best = c;
                }
            }
        }

        // serial in-order conflict resolution across the wave (register speed)
        u64 havemask = __ballot(best != ~0ull);
        while (havemask) {
            const int l = (int)(__ffsll((long long)havemask) - 1);
            havemask &= havemask - 1;
            const u32 blo = (u32)__builtin_amdgcn_readlane((int)(u32)best, l);
            const u32 bhi = (u32)__builtin_amdgcn_readlane((int)(u32)(best >> 32), l);
            const u64 bl  = ((u64)bhi << 32) | blo;
            if (bl == ~0ull) continue;   // lane l's pick was stolen and recompute failed

            if (lane == (u32)l) {
                // commit (index order preserved): suppress + accumulate
                s_sup[blo] = 1;
                float d = __uint_as_float(bhi);
                my_sum_dist += d;
                float diff = tp - s_pp[blo];
                my_sum_sq += diff * diff;
                my_cnt++;
            }
            if (lane > (u32)l && best != ~0ull && (u32)best == blo) {
                // pick stolen: rescan candidate list vs updated suppression
                best = ~0ull;
                if (coff != 0x1FFFu) {
                    for (u32 kk = 0; kk < eff; ++kk) {
                        u64 c = s_cand[coff + kk];
                        if (!s_sup[(u32)c] && c < best) best = c;
                    }
                } else {
                    for (u32 kk = 0; kk < eff; ++kk) {
                        u64 c = cands[(size_t)gi * (size_t)cap + kk];
                        if (!s_sup[(u32)c] && c < best) best = c;
                    }
                }
            }
        }
    }

    // wave reduction
    for (int off = 32; off > 0; off >>= 1) {
        my_sum_dist += __shfl_down(my_sum_dist, off, 64);
        my_sum_sq   += __shfl_down(my_sum_sq,   off, 64);
        my_cnt      += __shfl_down(my_cnt,      off, 64);
    }

    if (lane == 0) {
        float num_true  = (float)num_true_i;
        float cnt_f     = (float)my_cnt;
        float unmatched = num_true - cnt_f;
        float denom     = fmaxf(cnt_f, 1.0f);
        bool  has       = my_cnt > 0;
        float spatial   = RADIUS_F * 10.0f * unmatched + (has ? my_sum_dist / denom : 0.0f);
        float prob      = unmatched + (has ? my_sum_sq / denom : 0.0f);
        out[0] = spatial + prob;
    }
}

// ---------------- launch ----------------
extern "C" void kernel_launch(void* const* d_in, const int* in_sizes, int n_in,
                              void* d_out, int out_size, void* d_ws, size_t ws_size,
                              hipStream_t stream) {
    const float4* pred = (const float4*)d_in[0];
    const float4* tru  = (const float4*)d_in[1];
    const int n_pred = in_sizes[0] / 4;
    const int n_true = in_sizes[1] / 4;

    u32* counts = (u32*)d_ws;
    size_t counts_bytes = (size_t)n_true * sizeof(u32);
    size_t cand_off = (counts_bytes + 255) & ~(size_t)255;
    u64* cands = (u64*)((char*)d_ws + cand_off);

    int cap = 64;
    size_t need = cand_off + (size_t)n_true * (size_t)cap * 8;
    if (need > ws_size) {
        size_t avail = (ws_size > cand_off) ? (ws_size - cand_off) : 0;
        long c = (long)(avail / ((size_t)n_true * 8));
        cap = (int)(c < 1 ? 1 : (c > 64 ? 64 : c));
    }

    hipMemsetAsync(d_ws, 0, counts_bytes, stream);

    dim3 g1((n_pred + 255) / 256, (n_true + K1_TT - 1) / K1_TT);
    k_build<<<g1, 256, 0, stream>>>(pred, tru, n_pred, n_true, cap, counts, cands);
    k_match<<<1, K2_THREADS, 0, stream>>>(pred, tru, n_pred, n_true, cap, counts, cands,
                                          (float*)d_out);
}

// Round 3
// 60.308 us; speedup vs baseline: 4.9554x; 2.5112x over previous
//
#include <hip/hip_runtime.h>
#include <stdint.h>

typedef unsigned int u32;
typedef unsigned long long u64;

#define OCC_THR   0.5f
#define RADIUS_F  1.0f
#define MAXP      8192
#define K1_TT     128
#define K2_THREADS 512
#define PER       8   // true points per thread (4096 / 512)

// ---------------- Kernel 1: build candidate lists ----------------
// For every (true i, pred j) with pred_p[j] >= 0.5 and sqrt(d2) <= 1.0,
// append key = (dist_bits << 32) | j to cands[i*cap ...] via atomic slot.
__global__ void __launch_bounds__(256) k_build(
    const float4* __restrict__ pred, const float4* __restrict__ tru,
    int n_pred, int n_true, int cap,
    u32* __restrict__ counts, u64* __restrict__ cands)
{
    __shared__ float4 st[K1_TT];
    const int tid = threadIdx.x;
    const int j   = blockIdx.x * 256 + tid;
    const int ti0 = blockIdx.y * K1_TT;

    for (int t = tid; t < K1_TT; t += 256) {
        int i = ti0 + t;
        st[t] = (i < n_true) ? tru[i] : make_float4(1e30f, 1e30f, 1e30f, 0.0f);
    }
    __syncthreads();

    if (j >= n_pred) return;
    const float4 p = pred[j];
    if (!(p.w >= OCC_THR)) return;

    const int tmax = min(K1_TT, n_true - ti0);
    for (int t = 0; t < tmax; ++t) {
        float4 q = st[t];
        float dx = q.x - p.x, dy = q.y - p.y, dz = q.z - p.z;
        float d2 = dx*dx + dy*dy + dz*dz;
        float d  = sqrtf(d2);
        if (d <= RADIUS_F) {
            int i = ti0 + t;
            u32 slot = atomicAdd(&counts[i], 1u);
            if ((int)slot < cap) {
                u64 key = ((u64)__float_as_uint(d) << 32) | (u32)j;
                cands[(size_t)i * (size_t)cap + slot] = key;
            }
        }
    }
}

// ---------------- Kernel 2: parallel exact greedy via deferred acceptance ----
// Sequential greedy (serial dictatorship by true index) == unique stable
// matching when all preds rank positions by the same global order (the tag).
// Gale-Shapley fixpoint computes it order-independently:
//   owner[j] = min tag that has successfully proposed to j (atomicMin).
//   Availability (owner[j] > tag) is monotone-shrinking => rescans exact.
__global__ void __launch_bounds__(K2_THREADS) k_match(
    const float4* __restrict__ pred, const float4* __restrict__ tru,
    int n_pred, int n_true, int cap,
    const u32* __restrict__ counts,
    const u64* __restrict__ cands,
    float* __restrict__ out)
{
    __shared__ u32   s_owner[MAXP];   // 32 KB
    __shared__ int   s_flag;
    __shared__ int   s_numtrue;
    __shared__ float s_rd[8], s_rq[8];
    __shared__ int   s_rc[8];

    const int tid = threadIdx.x;
    if (tid == 0) s_numtrue = 0;
    for (int j = tid; j < MAXP; j += K2_THREADS) s_owner[j] = 0xFFFFFFFFu;

    // per-position state (all indices static via full unroll)
    u32  eff[PER];  float tp[PER];  u32 curj[PER];  float dist[PER];
    bool searching[PER];
    int myvalid = 0;
#pragma unroll
    for (int k = 0; k < PER; ++k) {
        const int i = tid * PER + k;
        eff[k] = 0; tp[k] = 0.0f; curj[k] = 0xFFFFFFFFu; dist[k] = 0.0f;
        searching[k] = false;
        if (i < n_true) {
            float4 q = tru[i];
            tp[k] = q.w;
            if (q.w >= OCC_THR) {
                myvalid++;
                u32 c = counts[i];
                if (c > (u32)cap) c = (u32)cap;
                eff[k] = c;
                searching[k] = (c > 0u);
            }
        }
    }
    if (myvalid) atomicAdd(&s_numtrue, myvalid);
    __syncthreads();

    // ---- deferred-acceptance rounds ----
    for (;;) {
        if (tid == 0) s_flag = 0;
        __syncthreads();

        u64 prop[PER];
#pragma unroll
        for (int k = 0; k < PER; ++k) {
            prop[k] = ~0ull;
            if (searching[k]) {
                const int i = tid * PER + k;
                const u64* row = &cands[(size_t)i * (size_t)cap];
                u64 best = ~0ull;
                for (u32 kk = 0; kk < eff[k]; ++kk) {
                    u64 c = row[kk];
                    if (s_owner[(u32)c] > (u32)i && c < best) best = c;
                }
                if (best != ~0ull) {
                    atomicMin(&s_owner[(u32)best], (u32)i);
                    prop[k] = best;
                } else {
                    searching[k] = false;   // exhausted -> final unmatched
                }
            }
        }
        __syncthreads();

        bool any = false;
#pragma unroll
        for (int k = 0; k < PER; ++k) {
            const int i = tid * PER + k;
            if (prop[k] != ~0ull) {
                const u32 j = (u32)prop[k];
                if (s_owner[j] == (u32)i) {          // proposal won (may still be evicted later)
                    curj[k] = j;
                    dist[k] = __uint_as_float((u32)(prop[k] >> 32));
                    searching[k] = false;
                } else {
                    any = true;                       // rejected -> retry
                }
            } else if (curj[k] != 0xFFFFFFFFu) {
                if (s_owner[curj[k]] != (u32)i) {     // evicted by a lower tag
                    curj[k] = 0xFFFFFFFFu;
                    searching[k] = true;
                    any = true;
                }
            }
        }
        if (any) s_flag = 1;
        __syncthreads();
        if (!s_flag) break;
    }

    // ---- accumulate ----
    float sd = 0.0f, sq = 0.0f; int cnt = 0;
#pragma unroll
    for (int k = 0; k < PER; ++k) {
        if (curj[k] != 0xFFFFFFFFu) {
            sd += dist[k];
            float pw = pred[curj[k]].w;               // scattered, L2-hot
            float df = tp[k] - pw;
            sq += df * df;
            cnt++;
        }
    }
    for (int off = 32; off > 0; off >>= 1) {
        sd  += __shfl_down(sd,  off, 64);
        sq  += __shfl_down(sq,  off, 64);
        cnt += __shfl_down(cnt, off, 64);
    }
    const int wave = tid >> 6;
    if ((tid & 63) == 0) { s_rd[wave] = sd; s_rq[wave] = sq; s_rc[wave] = cnt; }
    __syncthreads();

    if (tid == 0) {
        float tsd = 0.0f, tsq = 0.0f; int tc = 0;
        for (int w = 0; w < K2_THREADS / 64; ++w) { tsd += s_rd[w]; tsq += s_rq[w]; tc += s_rc[w]; }
        float num_true  = (float)s_numtrue;
        float cnt_f     = (float)tc;
        float unmatched = num_true - cnt_f;
        float denom     = fmaxf(cnt_f, 1.0f);
        bool  has       = tc > 0;
        float spatial   = RADIUS_F * 10.0f * unmatched + (has ? tsd / denom : 0.0f);
        float prob      = unmatched + (has ? tsq / denom : 0.0f);
        out[0] = spatial + prob;
    }
}

// ---------------- launch ----------------
extern "C" void kernel_launch(void* const* d_in, const int* in_sizes, int n_in,
                              void* d_out, int out_size, void* d_ws, size_t ws_size,
                              hipStream_t stream) {
    const float4* pred = (const float4*)d_in[0];
    const float4* tru  = (const float4*)d_in[1];
    const int n_pred = in_sizes[0] / 4;
    const int n_true = in_sizes[1] / 4;

    u32* counts = (u32*)d_ws;
    size_t counts_bytes = (size_t)n_true * sizeof(u32);
    size_t cand_off = (counts_bytes + 255) & ~(size_t)255;
    u64* cands = (u64*)((char*)d_ws + cand_off);

    int cap = 64;
    size_t need = cand_off + (size_t)n_true * (size_t)cap * 8;
    if (need > ws_size) {
        size_t avail = (ws_size > cand_off) ? (ws_size - cand_off) : 0;
        long c = (long)(avail / ((size_t)n_true * 8));
        cap = (int)(c < 1 ? 1 : (c > 64 ? 64 : c));
    }

    hipMemsetAsync(d_ws, 0, counts_bytes, stream);

    dim3 g1((n_pred + 255) / 256, (n_true + K1_TT - 1) / K1_TT);
    k_build<<<g1, 256, 0, stream>>>(pred, tru, n_pred, n_true, cap, counts, cands);
    k_match<<<1, K2_THREADS, 0, stream>>>(pred, tru, n_pred, n_true, cap, counts, cands,
                                          (float*)d_out);
}